// Round 4
// baseline (275.907 us; speedup 1.0000x reference)
//
#include <hip/hip_runtime.h>

// LengthRegulator: expand x[B,L,D] along L per integer durations into out[B,T,D].
// B=64, L=256, D=512, T=max_length=1792 (fixed by setup_inputs).
// Output tuple: (out [B,T,D] f32, max_length scalar) -> d_out flat, f32.
//
// Two kernels: (1) per-row duration totals -> d_ws (lets expand blocks whose
// tile lies entirely beyond `total` stream zeros with no scan/barriers);
// (2) expand with in-LDS scan + direct scatter for the frame->phoneme map.

#define BB 64
#define LL 256
#define DD 512
#define TT 1792
#define D4 (DD / 4)   // 128 float4 per row
#define TILE 64       // output frames per block (28 tiles, T = 28*64 exact)

// native vector type: __builtin_nontemporal_store rejects HIP_vector_type
typedef float vfloat4 __attribute__((ext_vector_type(4)));

__global__ __launch_bounds__(256) void row_totals_kernel(
    const int* __restrict__ dur,     // [B, L]
    const int* __restrict__ maxlen,  // [1]
    int*       __restrict__ totals,  // [B] (d_ws)
    float*     __restrict__ out)     // for the trailing scalar
{
    __shared__ int red[256];
    const int b = blockIdx.x, tid = threadIdx.x;
    red[tid] = dur[b * LL + tid];
    __syncthreads();
    #pragma unroll
    for (int off = 128; off > 0; off >>= 1) {
        if (tid < off) red[tid] += red[tid + off];
        __syncthreads();
    }
    if (tid == 0) {
        const int s = red[0];
        totals[b] = (s == 0) ? 1 : s;  // all-zero row gets one frame
        if (b == 0) out[(size_t)BB * TT * DD] = (float)maxlen[0];
    }
}

__global__ __launch_bounds__(256) void expand_kernel(
    const vfloat4* __restrict__ x4,     // [B, L, D4]
    const int*     __restrict__ dur,    // [B, L]
    const int*     __restrict__ totals, // [B]
    float*         __restrict__ out)    // [B*T*D + 1]
{
    const int tid   = threadIdx.x;
    const int b     = blockIdx.y;
    const int t0    = blockIdx.x * TILE;
    const int total = totals[b];
    vfloat4* out4   = (vfloat4*)out;
    const int group = tid >> 7;   // 0..1 (two 128-lane groups)
    const int lane  = tid & 127;  // float4 index within D-row

    if (t0 >= total) {
        // whole tile beyond sequence end: pure zero streaming, no LDS/barriers
        const vfloat4 z = (vfloat4)(0.f);
        #pragma unroll
        for (int j = 0; j < TILE / 2; ++j) {
            const int t = t0 + j * 2 + group;
            __builtin_nontemporal_store(z, &out4[((size_t)b * TT + t) * D4 + lane]);
        }
        return;
    }

    __shared__ int cum[LL];
    __shared__ int sidx[TILE];
    cum[tid] = dur[b * LL + tid];   // ALPHA=1.0 -> round(d*1.0)==d
    if (tid < TILE) sidx[tid] = 0;  // slots with t >= total are never read
    __syncthreads();

    // inclusive scan (Hillis-Steele, 8 steps)
    #pragma unroll
    for (int off = 1; off < LL; off <<= 1) {
        int v = (tid >= off) ? cum[tid - off] : 0;
        __syncthreads();
        cum[tid] += v;
        __syncthreads();
    }
    if (cum[LL - 1] == 0) cum[tid] = 1;  // all-zero row -> cum[j]=1 for all j
    __syncthreads();

    // frame->phoneme for this tile via direct scatter: thread tid owns
    // phoneme tid, frames [cum[tid-1], cum[tid])
    {
        const int end   = cum[tid];
        const int start = (tid == 0) ? 0 : cum[tid - 1];
        const int s = max(start, t0);
        const int e = min(end, t0 + TILE);
        for (int t = s; t < e; ++t) sidx[t - t0] = tid;
    }
    __syncthreads();

    // expand: each 128-lane group copies one D-row (2 KB) per iteration
    #pragma unroll 8
    for (int j = 0; j < TILE / 2; ++j) {
        const int t = t0 + j * 2 + group;
        vfloat4 val = (vfloat4)(0.f);
        if (t < total) {
            val = x4[((size_t)b * LL + sidx[j * 2 + group]) * D4 + lane];
        }
        __builtin_nontemporal_store(val, &out4[((size_t)b * TT + t) * D4 + lane]);
    }
}

extern "C" void kernel_launch(void* const* d_in, const int* in_sizes, int n_in,
                              void* d_out, int out_size, void* d_ws, size_t ws_size,
                              hipStream_t stream) {
    const vfloat4* x4  = (const vfloat4*)d_in[0];
    const int*     dur = (const int*)d_in[1];
    const int*     ml  = (const int*)d_in[2];
    float*         out = (float*)d_out;
    int*           tot = (int*)d_ws;  // 64 ints

    row_totals_kernel<<<dim3(BB), dim3(256), 0, stream>>>(dur, ml, tot, out);
    expand_kernel<<<dim3(TT / TILE, BB), dim3(256), 0, stream>>>(x4, dur, tot, out);
}